// Round 8
// baseline (276.736 us; speedup 1.0000x reference)
//
#include <hip/hip_runtime.h>
#include <math.h>

// EdgeFocusedGraphNetwork — fully folded, 6 plain launches.
//
// Algebra (HW-validated r1/r4/r7): fe rank-structured P[i]+Q[j]+r; softmax
// over i cancels Q,r,b_fe,b_ue,b_attn. New fold this round:
//   fv_{t+1} = fvm_t@Wfv.T + d_t,  Wfv = Wuv1@W_agg,
//   d_t = vb0 + Wuv2@agg_t (per-batch 256-vec), vb0 = Wuv1@b_agg + b_uv.
// Per step everything is expressed from {fvm_{t-1}, P_t, agg_{t-1}}:
//   S_t  = fvm_{t-1}@(Wsab@Wfv).T + (Wsab@d) + P_t@Wsa2.T
//   xh_t = mask ⊙ (fvm_{t-1}@(W_agg@Wfv).T + W_agg@d) + b_agg
//   P_{t+1} = fvm_{t-1}@(Wueb@Wfv).T + (Wueb@d) + P_t@Wue2.T
//   agg_t[b,h] = sigmoid(sum_i softmax_i(S)*xh)    (block-local per strip!)
// out = fvm_2@(W_oup@Wfv).T + (W_oup@d_2 + b_oup).
// Weight folds: Wsa=W_attn@W_ue; Wsab=Wsa1@Wfe1; Wueb=Wue1@Wfe1;
//   Wsab2=(Wsa1+Wsa2)@Wfe1; Wueb2=(Wue1+Wue2)@Wfe1 (P0 eliminated).
// Launches: prep -> folds1 -> (L0 + folds2) -> L1 -> L2 -> Lout.
// r7 lesson: 14 launches = ~190us of gaps; chain length is the cost.

typedef float f32x4  __attribute__((ext_vector_type(4)));
typedef short bf16x8 __attribute__((ext_vector_type(8)));

#define H  256
#define H2 512

__device__ __forceinline__ ushort f2bf(float f) {
    uint u = __float_as_uint(f);
    u += 0x7FFFu + ((u >> 16) & 1u);          // RNE
    return (ushort)(u >> 16);
}
__device__ __forceinline__ float bf2f(ushort h) {
    return __uint_as_float(((uint)h) << 16);
}

struct Args {
    const float *feat, *mask, *b_inp, *b_oup, *b_agg, *b_uv;
    const float *W_fe, *W_inp, *W_oup, *W_ue, *W_agg, *W_uv, *W_attn;
    float *out;
    // f32 ws
    float *Wsa1f, *Wsumf, *Wfvf, *Wsabf, *Wuebf, *vb0, *aggA, *aggB;
    // bf16 hi/lo planes
    ushort *fv0H,*fv0L, *fvm0H,*fvm0L, *fvm1H,*fvm1L, *fvm2H,*fvm2L,
           *p1H,*p1L, *p2H,*p2L,
           *Wsa2H,*Wsa2L, *WfvH,*WfvL, *WagPH,*WagPL, *Wue2H,*Wue2L,
           *Wsab2H,*Wsab2L, *Wueb2H,*Wueb2L, *WaggWfvH,*WaggWfvL,
           *WsabWfvH,*WsabWfvL, *WuebWfvH,*WuebWfvL, *WoupWfvH,*WoupWfvL;
};

// ---- 256-thr 32x32 f32 tile GEMM core (r1-validated pattern) --------------
// A row-major [.][lda]; aoff>0 adds A[i][k+aoff]. BT=1: Y=A@B.T (B [n][ldb]);
// BT=0: Y=A@B (B [k][ldb]). Elem (bi+2ty+dy, bj+2tx+dx) = acc[2*dy+dx].
__device__ void f32core(const float* __restrict__ A, int lda, int aoff,
                        const float* __restrict__ B, int ldb, int BT,
                        int K, int bi, int bj, int tid, float* lds, float acc[4])
{
    float* Xt = lds;          // [32][36] Xt[kk][i]
    float* Wt = lds + 1152;   // [32][36] Wt[kk][j]
    const int lr = tid >> 3, lc = (tid & 7) << 2;
    const int ty = tid >> 4, tx = tid & 15;
    acc[0] = acc[1] = acc[2] = acc[3] = 0.f;
    for (int k0 = 0; k0 < K; k0 += 32) {
        const float* ap = A + (size_t)(bi + lr) * lda + k0 + lc;
        float4 xv = *(const float4*)ap;
        if (aoff) {
            float4 x2 = *(const float4*)(ap + aoff);
            xv.x += x2.x; xv.y += x2.y; xv.z += x2.z; xv.w += x2.w;
        }
        float4 wv;
        if (BT) wv = *(const float4*)(B + (size_t)(bj + lr) * ldb + k0 + lc);
        else    wv = *(const float4*)(B + (size_t)(k0 + lr) * ldb + bj + lc);
        __syncthreads();
        Xt[(lc+0)*36+lr] = xv.x; Xt[(lc+1)*36+lr] = xv.y;
        Xt[(lc+2)*36+lr] = xv.z; Xt[(lc+3)*36+lr] = xv.w;
        if (BT) {
            Wt[(lc+0)*36+lr] = wv.x; Wt[(lc+1)*36+lr] = wv.y;
            Wt[(lc+2)*36+lr] = wv.z; Wt[(lc+3)*36+lr] = wv.w;
        } else {
            *(float4*)(Wt + lr*36 + lc) = wv;
        }
        __syncthreads();
        #pragma unroll
        for (int kk = 0; kk < 32; ++kk) {
            float2 x2 = *(const float2*)(Xt + kk*36 + 2*ty);
            float2 w2 = *(const float2*)(Wt + kk*36 + 2*tx);
            acc[0] = fmaf(x2.x, w2.x, acc[0]);
            acc[1] = fmaf(x2.x, w2.y, acc[1]);
            acc[2] = fmaf(x2.y, w2.x, acc[2]);
            acc[3] = fmaf(x2.y, w2.y, acc[3]);
        }
    }
}

__device__ __forceinline__ void ep_planes(ushort* yh, ushort* yl, int ld,
                                          int bi, int bj, int tid,
                                          const float acc[4])
{
    const int ty = tid >> 4, tx = tid & 15;
    #pragma unroll
    for (int dy = 0; dy < 2; ++dy)
        #pragma unroll
        for (int dx = 0; dx < 2; ++dx) {
            const int r = bi + 2*ty + dy, c = bj + 2*tx + dx;
            const float v = acc[2*dy + dx];
            const ushort hh = f2bf(v);
            yh[(size_t)r*ld + c] = hh;
            yl[(size_t)r*ld + c] = f2bf(v - bf2f(hh));
        }
}

// ---- one-wave 32x32 MFMA tile (r7-validated frags/CD map) -----------------
struct Seg { const ushort *ah,*al,*bh,*bl; int lda, ldb, nk32; };
#define M_S   0   // lds f32 [32][33]: acc (+vec)
#define M_XH  1   // lds f32: mask*(acc+vec)+bagg
#define M_P   2   // planes: acc (+vec)
#define M_FVM 3   // planes: (acc+vec)*mask
#define M_OUT 4   // f32 global: acc (+vec)

template<int MODE>
__device__ void wtile(const Seg* segs, int nseg, int grow, int gcol,
                      ushort* yh, ushort* yl, int ldy,
                      float* ldsOut,
                      float* yf, int ldyf,
                      const float* vec, const float* bagg, const float* mask,
                      int lane)
{
    const int rl = lane & 15, kq = lane >> 4;
    f32x4 acc[2][2] = {};
    for (int s = 0; s < nseg; ++s) {
        const Seg sg = segs[s];
        for (int ks = 0; ks < sg.nk32; ++ks) {
            const int kb = ks * 32 + kq * 8;
            bf16x8 ah[2], al[2], bh[2], bl[2];
            #pragma unroll
            for (int mi = 0; mi < 2; ++mi) {
                const size_t ro = (size_t)(grow + mi*16 + rl) * sg.lda + kb;
                ah[mi] = *(const bf16x8*)(sg.ah + ro);
                al[mi] = *(const bf16x8*)(sg.al + ro);
            }
            #pragma unroll
            for (int ni = 0; ni < 2; ++ni) {
                const size_t co = (size_t)(gcol + ni*16 + rl) * sg.ldb + kb;
                bh[ni] = *(const bf16x8*)(sg.bh + co);
                bl[ni] = *(const bf16x8*)(sg.bl + co);
            }
            #pragma unroll
            for (int mi = 0; mi < 2; ++mi)
                #pragma unroll
                for (int ni = 0; ni < 2; ++ni) {
                    acc[mi][ni] = __builtin_amdgcn_mfma_f32_16x16x32_bf16(
                        ah[mi], bh[ni], acc[mi][ni], 0, 0, 0);
                    acc[mi][ni] = __builtin_amdgcn_mfma_f32_16x16x32_bf16(
                        ah[mi], bl[ni], acc[mi][ni], 0, 0, 0);
                    acc[mi][ni] = __builtin_amdgcn_mfma_f32_16x16x32_bf16(
                        al[mi], bh[ni], acc[mi][ni], 0, 0, 0);
                }
        }
    }
    #pragma unroll
    for (int mi = 0; mi < 2; ++mi)
        #pragma unroll
        for (int ni = 0; ni < 2; ++ni) {
            const int lc = ni*16 + rl;
            #pragma unroll
            for (int j = 0; j < 4; ++j) {
                const int lr = mi*16 + kq*4 + j;
                float v = acc[mi][ni][j];
                if (vec) v += vec[lc];
                if (MODE == M_S) {
                    ldsOut[lr*33 + lc] = v;
                } else if (MODE == M_XH) {
                    if (mask) v *= mask[grow + lr];
                    v += bagg[gcol + lc];
                    ldsOut[lr*33 + lc] = v;
                } else if (MODE == M_P || MODE == M_FVM) {
                    if (MODE == M_FVM) v *= mask[grow + lr];
                    const ushort hh = f2bf(v);
                    yh[(size_t)(grow+lr)*ldy + gcol + lc] = hh;
                    yl[(size_t)(grow+lr)*ldy + gcol + lc] = f2bf(v - bf2f(hh));
                } else {
                    yf[(size_t)(grow+lr)*ldyf + gcol + lc] = v;
                }
            }
        }
}

// ---- L#1 prep: fv0 | Wsa | Wfv | splits+vb0  (448 blocks, raw inputs only)
__global__ __launch_bounds__(256) void k_prep(Args a)
{
    __shared__ float lds[2304];
    const int u = blockIdx.x, tid = threadIdx.x;
    float acc[4];
    if (u < 256) {                 // fv0 = feat@W_inp.T + b_inp -> fv0,fvm0
        const int bi = (u>>3)<<5, bj = (u&7)<<5;
        f32core(a.feat, 512, 0, a.W_inp, 512, 1, 512, bi, bj, tid, lds, acc);
        const int ty = tid>>4, tx = tid&15;
        #pragma unroll
        for (int dy = 0; dy < 2; ++dy)
            #pragma unroll
            for (int dx = 0; dx < 2; ++dx) {
                const int r = bi + 2*ty + dy, c = bj + 2*tx + dx;
                const float v = acc[2*dy+dx] + a.b_inp[c];
                ushort hh = f2bf(v);
                a.fv0H[r*H + c] = hh;
                a.fv0L[r*H + c] = f2bf(v - bf2f(hh));
                const float vm = v * a.mask[r];
                hh = f2bf(vm);
                a.fvm0H[r*H + c] = hh;
                a.fvm0L[r*H + c] = f2bf(vm - bf2f(hh));
            }
    } else if (u < 320) {          // Wsa = W_attn@W_ue (both halves + sum)
        const int v = u - 256;
        const int bi = (v>>3)<<5, bj = (v&7)<<5;
        float a2[4];
        f32core(a.W_attn, 256, 0, a.W_ue,       512, 0, 256, bi, bj, tid, lds, acc);
        f32core(a.W_attn, 256, 0, a.W_ue + 256, 512, 0, 256, bi, bj, tid, lds, a2);
        const int ty = tid>>4, tx = tid&15;
        #pragma unroll
        for (int dy = 0; dy < 2; ++dy)
            #pragma unroll
            for (int dx = 0; dx < 2; ++dx) {
                const int r = bi + 2*ty + dy, c = bj + 2*tx + dx;
                const float v1 = acc[2*dy+dx], v2 = a2[2*dy+dx];
                a.Wsa1f[r*H + c] = v1;
                a.Wsumf[r*H + c] = v1 + v2;
                const ushort hh = f2bf(v2);
                a.Wsa2H[r*H + c] = hh;
                a.Wsa2L[r*H + c] = f2bf(v2 - bf2f(hh));
            }
    } else if (u < 384) {          // Wfv = Wuv1@W_agg
        const int v = u - 320;
        const int bi = (v>>3)<<5, bj = (v&7)<<5;
        f32core(a.W_uv, 512, 0, a.W_agg, 256, 0, 256, bi, bj, tid, lds, acc);
        const int ty = tid>>4, tx = tid&15;
        #pragma unroll
        for (int dy = 0; dy < 2; ++dy)
            #pragma unroll
            for (int dx = 0; dx < 2; ++dx) {
                const int r = bi + 2*ty + dy, c = bj + 2*tx + dx;
                const float v1 = acc[2*dy+dx];
                a.Wfvf[r*H + c] = v1;
                const ushort hh = f2bf(v1);
                a.WfvH[r*H + c] = hh;
                a.WfvL[r*H + c] = f2bf(v1 - bf2f(hh));
            }
    } else {                       // splits: W_agg, Wue2 planes; vb0
        const int g = (u - 384) * 256 + tid;      // 0..16383
        #pragma unroll
        for (int q = 0; q < 4; ++q) {
            const int o = g*4 + q;
            float v1 = a.W_agg[o];
            ushort hh = f2bf(v1);
            a.WagPH[o] = hh; a.WagPL[o] = f2bf(v1 - bf2f(hh));
            const int n = o >> 8, k = o & 255;
            const float v2 = a.W_ue[n*512 + 256 + k];
            hh = f2bf(v2);
            a.Wue2H[o] = hh; a.Wue2L[o] = f2bf(v2 - bf2f(hh));
        }
        if (g < 256) {
            float s = a.b_uv[g];
            const float* wr = a.W_uv + (size_t)g * 512;
            for (int m = 0; m < 256; ++m) s = fmaf(wr[m], a.b_agg[m], s);
            a.vb0[g] = s;
        }
    }
}

// ---- L#2 folds1 (448 blocks) ----------------------------------------------
__global__ __launch_bounds__(256) void k_folds(Args a)
{
    __shared__ float lds[2304];
    const int u = blockIdx.x, tid = threadIdx.x;
    float acc[4];
    const int ty = tid>>4, tx = tid&15;
    if (u < 64) {                  // Wsab = Wsa1@Wfe1 (f32)
        const int bi = (u>>3)<<5, bj = (u&7)<<5;
        f32core(a.Wsa1f, 256, 0, a.W_fe, 512, 0, 256, bi, bj, tid, lds, acc);
        #pragma unroll
        for (int dy = 0; dy < 2; ++dy)
            #pragma unroll
            for (int dx = 0; dx < 2; ++dx)
                a.Wsabf[(bi+2*ty+dy)*H + bj+2*tx+dx] = acc[2*dy+dx];
    } else if (u < 128) {          // Wueb = Wue1@Wfe1 (f32)
        const int v = u-64, bi = (v>>3)<<5, bj = (v&7)<<5;
        f32core(a.W_ue, 512, 0, a.W_fe, 512, 0, 256, bi, bj, tid, lds, acc);
        #pragma unroll
        for (int dy = 0; dy < 2; ++dy)
            #pragma unroll
            for (int dx = 0; dx < 2; ++dx)
                a.Wuebf[(bi+2*ty+dy)*H + bj+2*tx+dx] = acc[2*dy+dx];
    } else if (u < 192) {          // Wsab2 = Wsum@Wfe1 -> planes
        const int v = u-128, bi = (v>>3)<<5, bj = (v&7)<<5;
        f32core(a.Wsumf, 256, 0, a.W_fe, 512, 0, 256, bi, bj, tid, lds, acc);
        ep_planes(a.Wsab2H, a.Wsab2L, H, bi, bj, tid, acc);
    } else if (u < 256) {          // Wueb2 = (Wue1+Wue2)@Wfe1 -> planes
        const int v = u-192, bi = (v>>3)<<5, bj = (v&7)<<5;
        f32core(a.W_ue, 512, 256, a.W_fe, 512, 0, 256, bi, bj, tid, lds, acc);
        ep_planes(a.Wueb2H, a.Wueb2L, H, bi, bj, tid, acc);
    } else if (u < 320) {          // WaggWfv = W_agg@Wfv -> planes
        const int v = u-256, bi = (v>>3)<<5, bj = (v&7)<<5;
        f32core(a.W_agg, 256, 0, a.Wfvf, 256, 0, 256, bi, bj, tid, lds, acc);
        ep_planes(a.WaggWfvH, a.WaggWfvL, H, bi, bj, tid, acc);
    } else {                       // WoupWfv = W_oup@Wfv -> planes (512 rows)
        const int v = u-320, bi = (v>>3)<<5, bj = (v&7)<<5;
        f32core(a.W_oup, 256, 0, a.Wfvf, 256, 0, 256, bi, bj, tid, lds, acc);
        ep_planes(a.WoupWfvH, a.WoupWfvL, H, bi, bj, tid, acc);
    }
}

// ---- L#3..5: per-step strips (+ folds2 tiles piggybacked on step 0) -------
__global__ __launch_bounds__(256) void k_step(Args a, int step)
{
    __shared__ float lds[9664];
    const int bid = blockIdx.x, tid = threadIdx.x;

    if (bid >= 64) {               // step-0 only: folds2 level-2 products
        int v = bid - 64;
        float acc[4];
        if (v < 64) {              // WsabWfv = Wsab@Wfv
            const int bi = (v>>3)<<5, bj = (v&7)<<5;
            f32core(a.Wsabf, 256, 0, a.Wfvf, 256, 0, 256, bi, bj, tid, lds, acc);
            ep_planes(a.WsabWfvH, a.WsabWfvL, H, bi, bj, tid, acc);
        } else {                   // WuebWfv = Wueb@Wfv
            v -= 64;
            const int bi = (v>>3)<<5, bj = (v&7)<<5;
            f32core(a.Wuebf, 256, 0, a.Wfvf, 256, 0, 256, bi, bj, tid, lds, acc);
            ep_planes(a.WuebWfvH, a.WuebWfvL, H, bi, bj, tid, acc);
        }
        return;
    }

    const int b = bid >> 3, hb = (bid & 7) << 5;
    const int rowb = b << 7;
    float* Sl  = lds;              // [128][33]
    float* Xl  = lds + 4224;       // [128][33]
    float* dV  = lds + 8448;       // d[256]
    float* sv  = lds + 8704;
    float* pv  = lds + 8736;
    float* xv  = lds + 8768;
    float* fvv = lds + 8800;
    float* red = lds + 8832;       // [3][256] partials
    float* Mv  = lds + 9600;       // [32]

    const float* aggIn  = (step == 2) ? a.aggB : a.aggA;
    float*       aggOut = (step == 1) ? a.aggB : a.aggA;

    if (step >= 1) {               // d + per-strip vector folds
        float dd = a.vb0[tid];
        const float* ag = aggIn + b * 256;
        const float* wr = a.W_uv + (size_t)tid * 512 + 256;
        for (int h = 0; h < 256; ++h) dd = fmaf(ag[h], wr[h], dd);
        dV[tid] = dd;
        __syncthreads();
        if (tid < 32) {
            float s = 0.f; const float* w = a.Wsabf + (size_t)(hb+tid)*H;
            for (int k = 0; k < 256; ++k) s = fmaf(w[k], dV[k], s);
            sv[tid] = s;
        } else if (tid < 64) {
            const int c = tid-32;
            float s = 0.f; const float* w = a.Wuebf + (size_t)(hb+c)*H;
            for (int k = 0; k < 256; ++k) s = fmaf(w[k], dV[k], s);
            pv[c] = s;
        } else if (tid < 96) {
            const int c = tid-64;
            float s = 0.f; const float* w = a.W_agg + (size_t)(hb+c)*H;
            for (int k = 0; k < 256; ++k) s = fmaf(w[k], dV[k], s);
            xv[c] = s;
        } else if (tid < 128) {
            fvv[tid-96] = dV[hb + tid-96];
        }
        __syncthreads();
    }

    const int lane = tid & 63, w = tid >> 6;
    const int grow = rowb + w * 32;
    float* SlW = Sl + w * 32 * 33;
    float* XlW = Xl + w * 32 * 33;
    Seg sg[2];

    if (step == 0) {
        sg[0] = {a.fv0H, a.fv0L, a.Wsab2H, a.Wsab2L, H, H, 8};
        wtile<M_S>(sg, 1, grow, hb, nullptr, nullptr, 0, SlW,
                   nullptr, 0, nullptr, nullptr, nullptr, lane);
        sg[0] = {a.fvm0H, a.fvm0L, a.WagPH, a.WagPL, H, H, 8};
        wtile<M_XH>(sg, 1, grow, hb, nullptr, nullptr, 0, XlW,
                    nullptr, 0, nullptr, a.b_agg, nullptr, lane);
        sg[0] = {a.fv0H, a.fv0L, a.Wueb2H, a.Wueb2L, H, H, 8};
        wtile<M_P>(sg, 1, grow, hb, a.p1H, a.p1L, H, nullptr,
                   nullptr, 0, nullptr, nullptr, nullptr, lane);
    } else {
        const ushort* fh = (step == 1) ? a.fvm0H : a.fvm1H;
        const ushort* fl = (step == 1) ? a.fvm0L : a.fvm1L;
        const ushort* ph = (step == 1) ? a.p1H : a.p2H;
        const ushort* pl = (step == 1) ? a.p1L : a.p2L;
        ushort* nfh = (step == 1) ? a.fvm1H : a.fvm2H;
        ushort* nfl = (step == 1) ? a.fvm1L : a.fvm2L;
        // fvm_t = (fvm_{t-1}@Wfv.T + d)*mask
        sg[0] = {fh, fl, a.WfvH, a.WfvL, H, H, 8};
        wtile<M_FVM>(sg, 1, grow, hb, nfh, nfl, H, nullptr,
                     nullptr, 0, fvv, nullptr, a.mask, lane);
        // S_t
        sg[0] = {fh, fl, a.WsabWfvH, a.WsabWfvL, H, H, 8};
        sg[1] = {ph, pl, a.Wsa2H, a.Wsa2L, H, H, 8};
        wtile<M_S>(sg, 2, grow, hb, nullptr, nullptr, 0, SlW,
                   nullptr, 0, sv, nullptr, nullptr, lane);
        // xh_t
        sg[0] = {fh, fl, a.WaggWfvH, a.WaggWfvL, H, H, 8};
        wtile<M_XH>(sg, 1, grow, hb, nullptr, nullptr, 0, XlW,
                    nullptr, 0, xv, a.b_agg, a.mask, lane);
        // P_{t+1} (step 1 only; P_3 is dead)
        if (step == 1) {
            sg[0] = {fh, fl, a.WuebWfvH, a.WuebWfvL, H, H, 8};
            sg[1] = {ph, pl, a.Wue2H, a.Wue2L, H, H, 8};
            wtile<M_P>(sg, 2, grow, hb, a.p2H, a.p2L, H, nullptr,
                       nullptr, 0, pv, nullptr, nullptr, lane);
        }
    }
    __syncthreads();

    // block-local softmax over i (128 rows) for this strip's 32 h-cols
    const int c = tid & 31, g = tid >> 5;          // 32 cols x 8 row-groups
    float m = -3.402823466e38f;
    #pragma unroll
    for (int r = 0; r < 16; ++r)
        m = fmaxf(m, Sl[(g*16 + r)*33 + c]);
    red[g*32 + c] = m;
    __syncthreads();
    if (g == 0) {
        float M = red[c];
        #pragma unroll
        for (int q = 1; q < 8; ++q) M = fmaxf(M, red[q*32 + c]);
        Mv[c] = M;
    }
    __syncthreads();
    const float M = Mv[c];
    float s = 0.f, ac = 0.f;
    #pragma unroll
    for (int r = 0; r < 16; ++r) {
        const int rr = (g*16 + r)*33 + c;
        const float e = __expf(Sl[rr] - M);
        s += e;
        ac = fmaf(e, Xl[rr], ac);
    }
    red[256 + g*32 + c] = s;
    red[512 + g*32 + c] = ac;
    __syncthreads();
    if (g == 0) {
        float S = 0.f, A = 0.f;
        #pragma unroll
        for (int q = 0; q < 8; ++q) {
            S += red[256 + q*32 + c];
            A += red[512 + q*32 + c];
        }
        aggOut[b*256 + hb + c] = 1.f / (1.f + __expf(-(A / S)));
    }
}

// ---- L#6: out = fvm2@(W_oup@Wfv).T + (W_oup@d2 + b_oup)  (128 blocks) -----
__global__ __launch_bounds__(256) void k_out(Args a)
{
    __shared__ float lds[304];
    float* d2 = lds; float* ov = lds + 256;
    const int b = blockIdx.x >> 4, nb = (blockIdx.x & 15) << 5;
    const int tid = threadIdx.x;
    float dd = a.vb0[tid];
    const float* ag = a.aggA + b * 256;
    const float* wr = a.W_uv + (size_t)tid * 512 + 256;
    for (int h = 0; h < 256; ++h) dd = fmaf(ag[h], wr[h], dd);
    d2[tid] = dd;
    __syncthreads();
    if (tid < 32) {
        float o = a.b_oup[nb + tid];
        const float* wo = a.W_oup + (size_t)(nb + tid) * 256;
        for (int k = 0; k < 256; ++k) o = fmaf(wo[k], d2[k], o);
        ov[tid] = o;
    }
    __syncthreads();
    const int lane = tid & 63, w = tid >> 6;
    Seg sg[1] = {{a.fvm2H, a.fvm2L, a.WoupWfvH, a.WoupWfvL, H, H, 8}};
    wtile<M_OUT>(sg, 1, b*128 + w*32, nb, nullptr, nullptr, 0, nullptr,
                 a.out, H2, ov, nullptr, nullptr, lane);
}

extern "C" void kernel_launch(void* const* d_in, const int* in_sizes, int n_in,
                              void* d_out, int out_size, void* d_ws, size_t ws_size,
                              hipStream_t stream)
{
    Args a;
    a.feat   = (const float*)d_in[0];
    a.mask   = (const float*)d_in[1];
    a.W_inp  = (const float*)d_in[2];
    a.b_inp  = (const float*)d_in[3];
    a.W_oup  = (const float*)d_in[4];
    a.b_oup  = (const float*)d_in[5];
    a.W_fe   = (const float*)d_in[6];   // [7] b_fe cancels
    a.W_ue   = (const float*)d_in[8];   // [9] b_ue cancels
    a.W_agg  = (const float*)d_in[10];
    a.b_agg  = (const float*)d_in[11];
    a.W_uv   = (const float*)d_in[12];
    a.b_uv   = (const float*)d_in[13];
    a.W_attn = (const float*)d_in[14];  // [15] b_attn cancels
    a.out    = (float*)d_out;

    float* fp = (float*)d_ws;
    auto takef = [&](int n) { float* p = fp; fp += n; return p; };
    a.Wsa1f = takef(65536); a.Wsumf = takef(65536); a.Wfvf = takef(65536);
    a.Wsabf = takef(65536); a.Wuebf = takef(65536);
    a.vb0 = takef(256); a.aggA = takef(2048); a.aggB = takef(2048);
    ushort* up = (ushort*)fp;
    auto take = [&](int n) { ushort* p = up; up += n; return p; };
    a.fv0H  = take(262144); a.fv0L  = take(262144);
    a.fvm0H = take(262144); a.fvm0L = take(262144);
    a.fvm1H = take(262144); a.fvm1L = take(262144);
    a.fvm2H = take(262144); a.fvm2L = take(262144);
    a.p1H   = take(262144); a.p1L   = take(262144);
    a.p2H   = take(262144); a.p2L   = take(262144);
    a.Wsa2H = take(65536);  a.Wsa2L = take(65536);
    a.WfvH  = take(65536);  a.WfvL  = take(65536);
    a.WagPH = take(65536);  a.WagPL = take(65536);
    a.Wue2H = take(65536);  a.Wue2L = take(65536);
    a.Wsab2H = take(65536); a.Wsab2L = take(65536);
    a.Wueb2H = take(65536); a.Wueb2L = take(65536);
    a.WaggWfvH = take(65536); a.WaggWfvL = take(65536);
    a.WsabWfvH = take(65536); a.WsabWfvL = take(65536);
    a.WuebWfvH = take(65536); a.WuebWfvL = take(65536);
    a.WoupWfvH = take(131072); a.WoupWfvL = take(131072);

    k_prep <<<dim3(448), dim3(256), 0, stream>>>(a);
    k_folds<<<dim3(448), dim3(256), 0, stream>>>(a);
    k_step <<<dim3(192), dim3(256), 0, stream>>>(a, 0);   // strips + folds2
    k_step <<<dim3(64),  dim3(256), 0, stream>>>(a, 1);
    k_step <<<dim3(64),  dim3(256), 0, stream>>>(a, 2);
    k_out  <<<dim3(128), dim3(256), 0, stream>>>(a);
}